// Round 9
// baseline (229.514 us; speedup 1.0000x reference)
//
#include <hip/hip_runtime.h>

#define HEADS 6
#define HD 16
#define NTOK 512
#define PD 6

typedef unsigned short u16;
typedef unsigned int u32;
typedef float f32x4 __attribute__((ext_vector_type(4)));
typedef short bf16x8 __attribute__((ext_vector_type(8)));
typedef u32 u32x4 __attribute__((ext_vector_type(4)));
typedef u32 u32x2 __attribute__((ext_vector_type(2)));

#define LOG2E 1.442695041f
#define QSCALE 0.360673760f   /* 0.25 * log2(e) folded into scaled operand */

__device__ __forceinline__ int sigma(int t) {
    return (t >> 6) + ((t >> 3) & 7) + (t & 7);
}

// fp32 -> (bf16 hi, bf16 lo) split (RNE both); hi+lo ~ 2^-17 relative accuracy
__device__ __forceinline__ void split2(float x, u16& hi, u16& lo) {
    u32 u = __float_as_uint(x);
    u32 rh = (u + 0x7fffu + ((u >> 16) & 1u)) & 0xffff0000u;
    hi = (u16)(rh >> 16);
    float xl = x - __uint_as_float(rh);
    u32 ul = __float_as_uint(xl);
    lo = (u16)((ul + 0x7fffu + ((ul >> 16) & 1u)) >> 16);
}

__device__ __forceinline__ void split8_store(float4 a, float4 b, float s,
                                             u16* hidst, u16* lodst) {
    ushort4 h0, h1, l0, l1;
    split2(a.x * s, h0.x, l0.x); split2(a.y * s, h0.y, l0.y);
    split2(a.z * s, h0.z, l0.z); split2(a.w * s, h0.w, l0.w);
    split2(b.x * s, h1.x, l1.x); split2(b.y * s, h1.y, l1.y);
    split2(b.z * s, h1.z, l1.z); split2(b.w * s, h1.w, l1.w);
    *(ushort4*)hidst = h0; *(ushort4*)(hidst + 4) = h1;
    *(ushort4*)lodst = l0; *(ushort4*)(lodst + 4) = l1;
}

// -------- tiny pos-MLP device body: 2 branches x 43 rows x 6 heads --------
__device__ void ln_relu_lin(const float* x, const float* g, const float* b,
                            const float* W, const float* bb, float* y) {
    float mu = 0.f;
#pragma unroll
    for (int k = 0; k < PD; ++k) mu += x[k];
    mu *= (1.f / PD);
    float var = 0.f;
#pragma unroll
    for (int k = 0; k < PD; ++k) { float d = x[k] - mu; var += d * d; }
    var *= (1.f / PD);
    float r = rsqrtf(var + 1e-5f);
    float t[PD];
#pragma unroll
    for (int k = 0; k < PD; ++k) {
        float v = (x[k] - mu) * r * g[k] + b[k];
        t[k] = fmaxf(v, 0.f);
    }
#pragma unroll
    for (int p = 0; p < PD; ++p) {
        float s = bb[p];
#pragma unroll
        for (int k = 0; k < PD; ++k) s = fmaf(t[k], W[p * PD + k], s);
        y[p] = s;
    }
}

__device__ void pos_mlp_body(
    int t,
    const float* w0, const float* b0, const float* g1, const float* be1,
    const float* w1, const float* bb1, const float* g2, const float* be2,
    const float* w2, const float* bb2, const float* g3, const float* be3,
    const float* w3, const float* bb3, float* tab)
{
    if (t >= 2 * 43) return;
    int br = t / 43;
    int j = t - br * 43;
    float bx = -7.f, by = -7.f + (float)(j / 15), bz = -7.f + (float)(j % 15);
    float x[PD], y[PD];
    const float* W = w0 + br * (PD * 3);
#pragma unroll
    for (int p = 0; p < PD; ++p)
        x[p] = bx * W[p * 3 + 0] + by * W[p * 3 + 1] +
               bz * W[p * 3 + 2] + b0[br * PD + p];
    ln_relu_lin(x, g1 + br * PD, be1 + br * PD, w1 + br * PD * PD, bb1 + br * PD, y);
    ln_relu_lin(y, g2 + br * PD, be2 + br * PD, w2 + br * PD * PD, bb2 + br * PD, x);
    ln_relu_lin(x, g3 + br * PD, be3 + br * PD, w3 + br * HEADS * PD, bb3 + br * HEADS, y);
#pragma unroll
    for (int hh = 0; hh < HEADS; ++hh)
        tab[(br * HEADS + hh) * 64 + j] = y[hh];
}

// -------- prekernel: split grid/qkv into bf16 hi|lo rows + packed V + pos-MLP --------
__global__ __launch_bounds__(256) void pre_kernel(
    const float* __restrict__ qkv, const float* __restrict__ grd,
    u16* __restrict__ Gs, u16* __restrict__ K0s, u16* __restrict__ Q1s,
    u32* __restrict__ V0p,
    const float* w0, const float* b0, const float* g1, const float* be1,
    const float* w1, const float* bb1, const float* g2, const float* be2,
    const float* w2, const float* bb2, const float* g3, const float* be3,
    const float* w3, const float* bb3, float* __restrict__ tab)
{
    __shared__ u32 vt[16 * 128];
    const int bid = blockIdx.x;
    const int tid = threadIdx.x;
    if (bid >= 2304) {
        pos_mlp_body(tid, w0, b0, g1, be1, w1, bb1, g2, be2, w2, bb2,
                     g3, be3, w3, bb3, tab);
        return;
    }
    const int is_qkv = (bid >= 1152);
    const int lb = is_qkv ? bid - 1152 : bid;
    const int pair = lb >> 2, jb = lb & 3;
    const int b = pair / HEADS, h = pair - (pair / HEADS) * HEADS;
    const int row = tid >> 1, half = tid & 1;
    const int j = jb * 128 + row;

    if (!is_qkv) {
        const float* src = grd + ((size_t)b * NTOK + j) * 96 + h * HD + half * 8;
        u16* dst = Gs + ((size_t)pair * NTOK + j) * 40 + half * 8;
        split8_store(*(const float4*)src, *(const float4*)(src + 4), 1.f,
                     dst, dst + 16);
        return;
    }
    const float* base = qkv + ((size_t)b * NTOK + j) * 288 + h * HD + half * 8;
    {   // K slice (scaled)
        u16* dst = K0s + ((size_t)pair * NTOK + j) * 40 + half * 8;
        split8_store(*(const float4*)(base + 96), *(const float4*)(base + 100),
                     QSCALE, dst, dst + 16);
    }
    {   // Q slice (scaled)
        u16* dst = Q1s + ((size_t)pair * NTOK + j) * 40 + half * 8;
        split8_store(*(const float4*)base, *(const float4*)(base + 4),
                     QSCALE, dst, dst + 16);
    }
    {   // V slice -> packed transpose via LDS
        float4 a = *(const float4*)(base + 192);
        float4 c = *(const float4*)(base + 196);
        float vv[8] = {a.x, a.y, a.z, a.w, c.x, c.y, c.z, c.w};
#pragma unroll
        for (int s = 0; s < 8; ++s) {
            u16 hh, ll; split2(vv[s], hh, ll);
            vt[(half * 8 + s) * 128 + row] = (u32)hh | ((u32)ll << 16);
        }
    }
    __syncthreads();
    const int c = tid >> 4, jc = (tid & 15) * 8;
    u32* vdst = V0p + (size_t)pair * 8192 + c * NTOK + jb * 128 + jc;
    *(u32x4*)vdst = *(const u32x4*)&vt[c * 128 + jc];
    *(u32x4*)(vdst + 4) = *(const u32x4*)&vt[c * 128 + jc + 4];
}

// -------- MFMA attention pass, 64 q-rows/block for TLP --------
// grid 2304 = 288 pairs x 8 row-blocks of 64 q-rows; 256 thr = 4 waves;
// wave w owns rows [Iblk+16w, +16) as ONE 16-row tile, iterates all 512 j.
// r8's validated structure with qi collapsed: K rows staged PERMUTED so
// S^T's C-layout output IS the PV B-operand layout (P register->register);
// V as A operand from packed [c][j]; l0 via ones-as-A MFMA (in-lane).
// 17.1 KB LDS + low VGPR -> 8 blocks/CU (was 4.5), hiding the serial
// S-mfma -> exp -> pack -> PV chain that bounded r8 at ~375 cyc/g.
__global__ __launch_bounds__(256) void attn4_kernel(
    int pass, const u16* __restrict__ Qrows, const u16* __restrict__ Krows,
    const u32* __restrict__ Vpack, const float* __restrict__ tab,
    u32* __restrict__ xout, float* __restrict__ outp)
{
    __shared__ __align__(16) u16 sQ[64 * 48];    // [Qhi16|Qlo16|zeros16]
    __shared__ __align__(16) u16 sK[128 * 40];   // [Khi16|Klo16|pad8], permuted
    __shared__ __align__(16) f32x4 rt2[46];      // rpb*log2e, descending 4-tuple

    const int pair = blockIdx.x >> 3;
    const int rb = blockIdx.x & 7;
    const int Iblk = rb * 64;
    const int b = pair / HEADS, h = pair - (pair / HEADS) * HEADS;
    const int tid = threadIdx.x, lane = tid & 63, w = tid >> 6;
    const int l15 = lane & 15, q = lane >> 4, q8 = q * 8;

    if (tid < 46) {
        const float* tb = tab + (pass * HEADS + h) * 64;
        f32x4 v;
#pragma unroll
        for (int c = 0; c < 4; ++c) {
            int ix = tid - c; ix = ix < 0 ? 0 : (ix > 42 ? 42 : ix);
            v[c] = tb[ix] * LOG2E;
        }
        rt2[tid] = v;
    }
    {   // stage Q: 64 rows x 16 u32 payload into 24-u32-stride rows + zero pad
        const u32* qsrc = (const u32*)(Qrows + ((size_t)pair * NTOK + Iblk) * 40);
        int row = tid >> 2, ch = tid & 3;
        *(u32x4*)&((u32*)sQ)[row * 24 + ch * 4] =
            *(const u32x4*)&qsrc[row * 20 + ch * 4];
#pragma unroll
        for (int k = 0; k < 2; ++k) {
            int item = tid + k * 256;
            ((u32*)sQ)[(item >> 3) * 24 + 16 + (item & 7)] = 0;
        }
    }
    __syncthreads();

    const int sA = sigma(Iblk + w * 16 + l15) + 21;
    bf16x8 B1, B2;
    {
        int row = w * 16 + l15;
        B1 = *(const bf16x8*)&sQ[row * 48 + (q & 1) * 8];
        B2 = *(const bf16x8*)&sQ[row * 48 + 16 + q8];
    }
    f32x4 accO = {0.f, 0.f, 0.f, 0.f};
    f32x4 accL = {0.f, 0.f, 0.f, 0.f};
    bf16x8 vones = {(short)0x3F80,(short)0x3F80,(short)0x3F80,(short)0x3F80,
                    (short)0x3F80,(short)0x3F80,(short)0x3F80,(short)0x3F80};
    const u32* vbase = Vpack + (size_t)pair * 8192 + l15 * NTOK;

    // K staging: thread copies half a row; target slot permuted so that
    // within each 32-token group, tile0 slot m holds token 8*(m>>2)+(m&3),
    // tile1 slot m holds that +4 (validated in r8, absmax 9.8e-4).
    const int srow = tid >> 1, shalf = tid & 1;
    const int t5 = srow & 31;
    const int sslot = (srow & 96) +
                      (((t5 & 4) << 2) | ((t5 >> 3) << 2) | (t5 & 3));
    const u32* ksbase = (const u32*)(Krows + (size_t)pair * NTOK * 40);
    u32* kdst = (u32*)sK + sslot * 20 + shalf * 8;

    for (int step = 0; step < 4; ++step) {
        const int Jblk = step * 128;
        __syncthreads();   // previous step's sK fully consumed
        {
            const u32* ks = ksbase + (size_t)(Jblk + srow) * 20 + shalf * 8;
            *(u32x4*)kdst = *(const u32x4*)ks;
            *(u32x4*)(kdst + 4) = *(const u32x4*)(ks + 4);
        }
        __syncthreads();

        u32x4 va = *(const u32x4*)(vbase + Jblk + q8);
        u32x4 vb = *(const u32x4*)(vbase + Jblk + q8 + 4);
        for (int g = 0; g < 4; ++g) {
            u32x4 nva, nvb;
            if (g < 3) {
                nva = *(const u32x4*)(vbase + Jblk + (g + 1) * 32 + q8);
                nvb = *(const u32x4*)(vbase + Jblk + (g + 1) * 32 + q8 + 4);
            }
            const int sJg = sigma(Jblk + g * 32);   // wave-uniform
            bf16x8 A0 = *(const bf16x8*)&sK[(g * 32 + l15) * 40 + q8];
            bf16x8 A1 = *(const bf16x8*)&sK[(g * 32 + 16 + l15) * 40 + q8];
            union { u32 u[4]; bf16x8 v; } VH, VL;
            VH.u[0] = __builtin_amdgcn_perm(va.y, va.x, 0x05040100u);
            VH.u[1] = __builtin_amdgcn_perm(va.w, va.z, 0x05040100u);
            VH.u[2] = __builtin_amdgcn_perm(vb.y, vb.x, 0x05040100u);
            VH.u[3] = __builtin_amdgcn_perm(vb.w, vb.z, 0x05040100u);
            VL.u[0] = __builtin_amdgcn_perm(va.y, va.x, 0x07060302u);
            VL.u[1] = __builtin_amdgcn_perm(va.w, va.z, 0x07060302u);
            VL.u[2] = __builtin_amdgcn_perm(vb.y, vb.x, 0x07060302u);
            VL.u[3] = __builtin_amdgcn_perm(vb.w, vb.z, 0x07060302u);

            f32x4 S0 = {0.f,0.f,0.f,0.f}, S1 = {0.f,0.f,0.f,0.f};
            S0 = __builtin_amdgcn_mfma_f32_16x16x32_bf16(A0, B1, S0, 0, 0, 0);
            S0 = __builtin_amdgcn_mfma_f32_16x16x32_bf16(A0, B2, S0, 0, 0, 0);
            S1 = __builtin_amdgcn_mfma_f32_16x16x32_bf16(A1, B1, S1, 0, 0, 0);
            S1 = __builtin_amdgcn_mfma_f32_16x16x32_bf16(A1, B2, S1, 0, 0, 0);
            // permuted rows: token(S0 reg r) = Jg + 8q + r -> rpb idx descends
            f32x4 rv0 = rt2[sA - sJg - q];
            f32x4 rv1 = rt2[sA - sJg - q - 4];
            u32 e0 = __float_as_uint(exp2f(S0.x + rv0.x));
            u32 e1 = __float_as_uint(exp2f(S0.y + rv0.y));
            u32 e2 = __float_as_uint(exp2f(S0.z + rv0.z));
            u32 e3 = __float_as_uint(exp2f(S0.w + rv0.w));
            u32 e4 = __float_as_uint(exp2f(S1.x + rv1.x));
            u32 e5 = __float_as_uint(exp2f(S1.y + rv1.y));
            u32 e6 = __float_as_uint(exp2f(S1.z + rv1.z));
            u32 e7 = __float_as_uint(exp2f(S1.w + rv1.w));
            union { u32 u[4]; bf16x8 v; } Pb;   // bf16-trunc pack, k-order
            Pb.u[0] = __builtin_amdgcn_perm(e1, e0, 0x07060302u);
            Pb.u[1] = __builtin_amdgcn_perm(e3, e2, 0x07060302u);
            Pb.u[2] = __builtin_amdgcn_perm(e5, e4, 0x07060302u);
            Pb.u[3] = __builtin_amdgcn_perm(e7, e6, 0x07060302u);
            accO = __builtin_amdgcn_mfma_f32_16x16x32_bf16(VH.v, Pb.v, accO, 0, 0, 0);
            accO = __builtin_amdgcn_mfma_f32_16x16x32_bf16(VL.v, Pb.v, accO, 0, 0, 0);
            accL = __builtin_amdgcn_mfma_f32_16x16x32_bf16(vones, Pb.v, accL, 0, 0, 0);
            va = nva; vb = nvb;
        }
    }

    // ---- epilogue: accO = O^T[c=4q+reg][i=l15]; accL[*] = l0[i] in-lane ----
    const float inv = 1.0f / accL[0];
    const int i = Iblk + w * 16 + l15;
    if (pass == 0) {
#pragma unroll
        for (int rg = 0; rg < 4; ++rg) {
            u16 hh, ll; split2(accO[rg] * inv, hh, ll);
            xout[(size_t)pair * 8192 + (size_t)(4 * q + rg) * NTOK + i] =
                (u32)hh | ((u32)ll << 16);
        }
    } else {
        float4 v = make_float4(accO[0] * inv, accO[1] * inv,
                               accO[2] * inv, accO[3] * inv);
        *(float4*)&outp[((size_t)b * NTOK + i) * 96 + h * HD + 4 * q] = v;
    }
}

// ================= fallback path (small ws): round-6 kernels =================
__global__ void pos_mlp_kernel(
    const float* w0, const float* b0, const float* g1, const float* be1,
    const float* w1, const float* bb1, const float* g2, const float* be2,
    const float* w2, const float* bb2, const float* g3, const float* be3,
    const float* w3, const float* bb3, float* tab)
{
    pos_mlp_body(threadIdx.x, w0, b0, g1, be1, w1, bb1, g2, be2, w2, bb2,
                 g3, be3, w3, bb3, tab);
}

__device__ __forceinline__ u32 rnd16(float p, float& l0acc) {
    u32 u = __float_as_uint(p);
    u32 r = u + 0x7fffu + ((u >> 16) & 1u);
    l0acc += __uint_as_float(r & 0xffff0000u);
    return r;
}

__global__ __launch_bounds__(256) void attn_v6_kernel(
    int pass,
    const float* __restrict__ qkv, const float* __restrict__ grd,
    const float* __restrict__ tab, float* __restrict__ xbuf,
    float* __restrict__ outp)
{
    __shared__ __align__(16) u16 sQ[128 * 48];
    __shared__ __align__(16) u16 sK[128 * 32];
    __shared__ __align__(16) u32 sV[16 * 132];
    __shared__ __align__(16) u16 sP[4 * 2 * 16 * 32];
    __shared__ __align__(16) f32x4 rt2[46];

    const int pair = blockIdx.x >> 2;
    const int rb   = blockIdx.x & 3;
    const int Iblk = rb * 128;
    const int b = pair / HEADS, h = pair - (pair / HEADS) * HEADS;
    const int tid = threadIdx.x;
    const int lane = tid & 63;
    const int w = tid >> 6;
    const int l15 = lane & 15;
    const int q = lane >> 4;
    const int q8 = q * 8;

    const float *qp, *kp, *vp, *tb;
    float* op;
    int qs, ks, vs, os;
    if (pass == 0) {
        qp = grd + (size_t)b * NTOK * 96 + h * HD;        qs = 96;
        kp = qkv + (size_t)b * NTOK * 288 + 96 + h * HD;  ks = 288;
        vp = kp + 96;                                     vs = 288;
        op = xbuf + (size_t)pair * NTOK * HD;             os = HD;
        tb = tab + h * 64;
    } else {
        qp = qkv + (size_t)b * NTOK * 288 + h * HD;       qs = 288;
        kp = grd + (size_t)b * NTOK * 96 + h * HD;        ks = 96;
        vp = xbuf + (size_t)pair * NTOK * HD;             vs = HD;
        op = outp + (size_t)b * NTOK * 96 + h * HD;       os = 96;
        tb = tab + (HEADS + h) * 64;
    }

#pragma unroll
    for (int k = 0; k < 2; ++k) {
        int item = tid + k * 256;
        int row = item >> 2, ch = item & 3;
        float4 u = *(const float4*)(qp + (size_t)(Iblk + row) * qs + ch * 4);
        ushort4 hi4, lo4;
        split2(u.x * QSCALE, hi4.x, lo4.x);
        split2(u.y * QSCALE, hi4.y, lo4.y);
        split2(u.z * QSCALE, hi4.z, lo4.z);
        split2(u.w * QSCALE, hi4.w, lo4.w);
        *(ushort4*)&sQ[row * 48 + ch * 4] = hi4;
        *(ushort4*)&sQ[row * 48 + 16 + ch * 4] = lo4;
    }
#pragma unroll
    for (int k = 0; k < 4; ++k) {
        int item = tid + k * 256;
        ((u32*)sQ)[(item >> 3) * 24 + 16 + (item & 7)] = 0;
    }
    if (tid < 46) {
        f32x4 v;
#pragma unroll
        for (int c = 0; c < 4; ++c) {
            int ix = tid - c; ix = ix < 0 ? 0 : (ix > 42 ? 42 : ix);
            v[c] = tb[ix] * LOG2E;
        }
        rt2[tid] = v;
    }
    __syncthreads();

    const int qoff = ((q & 1) << 2) | (q >> 1);
    int sA[2];
    sA[0] = sigma(Iblk + w * 32 + l15) + 21;
    sA[1] = sigma(Iblk + w * 32 + 16 + l15) + 21;
    bf16x8 B1[2], B2[2];
#pragma unroll
    for (int qi = 0; qi < 2; ++qi) {
        int row = w * 32 + qi * 16 + l15;
        B1[qi] = *(const bf16x8*)&sQ[row * 48 + (q & 1) * 8];
        B2[qi] = *(const bf16x8*)&sQ[row * 48 + 16 + q8];
    }
    f32x4 accO[2] = {{0.f,0.f,0.f,0.f},{0.f,0.f,0.f,0.f}};
    float l0a[2] = {0.f, 0.f};
    u32* sPu32 = (u32*)sP;

    for (int step = 0; step < 4; ++step) {
        const int Jblk = step * 128;
        if (step) __syncthreads();
#pragma unroll
        for (int k = 0; k < 2; ++k) {
            int item = tid + k * 256;
            int j = item >> 2, ch = item & 3;
            float4 u = *(const float4*)(kp + (size_t)(Jblk + j) * ks + ch * 4);
            ushort4 hi4, lo4;
            split2(u.x, hi4.x, lo4.x);
            split2(u.y, hi4.y, lo4.y);
            split2(u.z, hi4.z, lo4.z);
            split2(u.w, hi4.w, lo4.w);
            *(ushort4*)&sK[j * 32 + ch * 4] = hi4;
            *(ushort4*)&sK[j * 32 + 16 + ch * 4] = lo4;
            float4 vv = *(const float4*)(vp + (size_t)(Jblk + j) * vs + ch * 4);
            u16 vh, vl;
            split2(vv.x, vh, vl); sV[(ch * 4 + 0) * 132 + j] = (u32)vh | ((u32)vl << 16);
            split2(vv.y, vh, vl); sV[(ch * 4 + 1) * 132 + j] = (u32)vh | ((u32)vl << 16);
            split2(vv.z, vh, vl); sV[(ch * 4 + 2) * 132 + j] = (u32)vh | ((u32)vl << 16);
            split2(vv.w, vh, vl); sV[(ch * 4 + 3) * 132 + j] = (u32)vh | ((u32)vl << 16);
        }
        __syncthreads();

        for (int g = 0; g < 4; ++g) {
            const int sJ0 = sigma(Jblk + g * 32), sJ1 = sigma(Jblk + g * 32 + 16);
            bf16x8 A0 = *(const bf16x8*)&sK[(g * 32 + l15) * 32 + q8];
            bf16x8 A1 = *(const bf16x8*)&sK[(g * 32 + 16 + l15) * 32 + q8];
            const u32* vr = &sV[l15 * 132 + g * 32 + q8];
            u32x4 va = *(const u32x4*)vr;
            u32x4 vb = *(const u32x4*)(vr + 4);
            union { u32x4 u; bf16x8 hv; } BH, BL;
            BH.u[0] = __builtin_amdgcn_perm(va.y, va.x, 0x05040100u);
            BH.u[1] = __builtin_amdgcn_perm(va.w, va.z, 0x05040100u);
            BH.u[2] = __builtin_amdgcn_perm(vb.y, vb.x, 0x05040100u);
            BH.u[3] = __builtin_amdgcn_perm(vb.w, vb.z, 0x05040100u);
            BL.u[0] = __builtin_amdgcn_perm(va.y, va.x, 0x07060302u);
            BL.u[1] = __builtin_amdgcn_perm(va.w, va.z, 0x07060302u);
            BL.u[2] = __builtin_amdgcn_perm(vb.y, vb.x, 0x07060302u);
            BL.u[3] = __builtin_amdgcn_perm(vb.w, vb.z, 0x07060302u);

#pragma unroll
            for (int qi = 0; qi < 2; ++qi) {
                f32x4 S0 = {0.f,0.f,0.f,0.f}, S1 = {0.f,0.f,0.f,0.f};
                S0 = __builtin_amdgcn_mfma_f32_16x16x32_bf16(A0, B1[qi], S0, 0, 0, 0);
                S0 = __builtin_amdgcn_mfma_f32_16x16x32_bf16(A0, B2[qi], S0, 0, 0, 0);
                S1 = __builtin_amdgcn_mfma_f32_16x16x32_bf16(A1, B1[qi], S1, 0, 0, 0);
                S1 = __builtin_amdgcn_mfma_f32_16x16x32_bf16(A1, B2[qi], S1, 0, 0, 0);
                f32x4 rv0 = rt2[sA[qi] - sJ0 - qoff];
                f32x4 rv1 = rt2[sA[qi] - sJ1 - qoff];
                u32 r0 = rnd16(exp2f(S0.x + rv0.x), l0a[qi]);
                u32 r1 = rnd16(exp2f(S0.y + rv0.y), l0a[qi]);
                u32 r2 = rnd16(exp2f(S0.z + rv0.z), l0a[qi]);
                u32 r3 = rnd16(exp2f(S0.w + rv0.w), l0a[qi]);
                u32 pk01 = __builtin_amdgcn_perm(r1, r0, 0x07060302u);
                u32 pk23 = __builtin_amdgcn_perm(r3, r2, 0x07060302u);
                const int pbase = ((w * 2 + qi) * 16 + l15) * 16;
                *(uint2*)&sPu32[pbase + 2 * q] = make_uint2(pk01, pk23);
                r0 = rnd16(exp2f(S1.x + rv1.x), l0a[qi]);
                r1 = rnd16(exp2f(S1.y + rv1.y), l0a[qi]);
                r2 = rnd16(exp2f(S1.z + rv1.z), l0a[qi]);
                r3 = rnd16(exp2f(S1.w + rv1.w), l0a[qi]);
                pk01 = __builtin_amdgcn_perm(r1, r0, 0x07060302u);
                pk23 = __builtin_amdgcn_perm(r3, r2, 0x07060302u);
                *(uint2*)&sPu32[pbase + 8 + 2 * q] = make_uint2(pk01, pk23);
                bf16x8 Apv = *(const bf16x8*)&sP[((w * 2 + qi) * 16 + l15) * 32 + q8];
                accO[qi] = __builtin_amdgcn_mfma_f32_16x16x32_bf16(Apv, BH.hv, accO[qi], 0, 0, 0);
                accO[qi] = __builtin_amdgcn_mfma_f32_16x16x32_bf16(Apv, BL.hv, accO[qi], 0, 0, 0);
            }
        }
    }

#pragma unroll
    for (int qi = 0; qi < 2; ++qi) {
        float lt = l0a[qi];
        lt += __shfl_xor(lt, 16);
        lt += __shfl_xor(lt, 32);
#pragma unroll
        for (int rg = 0; rg < 4; ++rg) {
            float lr = __shfl(lt, q * 4 + rg);
            int ig = Iblk + w * 32 + qi * 16 + q * 4 + rg;
            op[(size_t)ig * os + l15] = accO[qi][rg] / lr;
        }
    }
}

extern "C" void kernel_launch(void* const* d_in, const int* in_sizes, int n_in,
                              void* d_out, int out_size, void* d_ws, size_t ws_size,
                              hipStream_t stream)
{
    const float* qkv = (const float*)d_in[0];
    const float* grd = (const float*)d_in[1];
    float* tab = (float*)d_ws;                          // 1024 f
    const size_t ROWS = (size_t)288 * NTOK;             // 147456 rows per tensor

    u32* xbuf = (u32*)(tab + 1024);                     // 288*8192 u32 = 9.44 MB
    u16* Gs   = (u16*)(xbuf + (size_t)288 * 8192);      // ROWS*40 u16 = 11.8 MB
    u16* K0s  = Gs + ROWS * 40;
    u16* Q1s  = K0s + ROWS * 40;
    u32* V0p  = (u32*)(Q1s + ROWS * 40);                // 9.44 MB
    const size_t NEEDED = 4096 + 9437184ull + 3ull * 11796480 + 9437184ull;

    if (ws_size >= NEEDED) {
        pre_kernel<<<2305, 256, 0, stream>>>(
            qkv, grd, Gs, K0s, Q1s, V0p,
            (const float*)d_in[2], (const float*)d_in[3],
            (const float*)d_in[4], (const float*)d_in[5],
            (const float*)d_in[6], (const float*)d_in[7],
            (const float*)d_in[8], (const float*)d_in[9],
            (const float*)d_in[10], (const float*)d_in[11],
            (const float*)d_in[12], (const float*)d_in[13],
            (const float*)d_in[14], (const float*)d_in[15],
            tab);
        attn4_kernel<<<2304, 256, 0, stream>>>(0, Gs, K0s, V0p, tab, xbuf, nullptr);
        attn4_kernel<<<2304, 256, 0, stream>>>(1, Q1s, Gs, xbuf, tab, nullptr, (float*)d_out);
    } else {
        float* xf = (float*)d_ws + 1024;
        pos_mlp_kernel<<<1, 128, 0, stream>>>(
            (const float*)d_in[2], (const float*)d_in[3],
            (const float*)d_in[4], (const float*)d_in[5],
            (const float*)d_in[6], (const float*)d_in[7],
            (const float*)d_in[8], (const float*)d_in[9],
            (const float*)d_in[10], (const float*)d_in[11],
            (const float*)d_in[12], (const float*)d_in[13],
            (const float*)d_in[14], (const float*)d_in[15],
            tab);
        attn_v6_kernel<<<1152, 256, 0, stream>>>(0, qkv, grd, tab, xf, nullptr);
        attn_v6_kernel<<<1152, 256, 0, stream>>>(1, qkv, grd, tab, xf, (float*)d_out);
    }
}

// Round 10
// 190.603 us; speedup vs baseline: 1.2041x; 1.2041x over previous
//
#include <hip/hip_runtime.h>

#define HEADS 6
#define HD 16
#define NTOK 512
#define PD 6

typedef unsigned short u16;
typedef unsigned int u32;
typedef float f32x4 __attribute__((ext_vector_type(4)));
typedef short bf16x8 __attribute__((ext_vector_type(8)));
typedef u32 u32x4 __attribute__((ext_vector_type(4)));
typedef u32 u32x2 __attribute__((ext_vector_type(2)));

#define LOG2E 1.442695041f
#define QSCALE 0.360673760f   /* 0.25 * log2(e) folded into scaled operand */

__device__ __forceinline__ int sigma(int t) {
    return (t >> 6) + ((t >> 3) & 7) + (t & 7);
}

// fp32 -> (bf16 hi, bf16 lo) split (RNE both); hi+lo ~ 2^-17 relative accuracy
__device__ __forceinline__ void split2(float x, u16& hi, u16& lo) {
    u32 u = __float_as_uint(x);
    u32 rh = (u + 0x7fffu + ((u >> 16) & 1u)) & 0xffff0000u;
    hi = (u16)(rh >> 16);
    float xl = x - __uint_as_float(rh);
    u32 ul = __float_as_uint(xl);
    lo = (u16)((ul + 0x7fffu + ((ul >> 16) & 1u)) >> 16);
}

__device__ __forceinline__ void split8_store(float4 a, float4 b, float s,
                                             u16* hidst, u16* lodst) {
    ushort4 h0, h1, l0, l1;
    split2(a.x * s, h0.x, l0.x); split2(a.y * s, h0.y, l0.y);
    split2(a.z * s, h0.z, l0.z); split2(a.w * s, h0.w, l0.w);
    split2(b.x * s, h1.x, l1.x); split2(b.y * s, h1.y, l1.y);
    split2(b.z * s, h1.z, l1.z); split2(b.w * s, h1.w, l1.w);
    *(ushort4*)hidst = h0; *(ushort4*)(hidst + 4) = h1;
    *(ushort4*)lodst = l0; *(ushort4*)(lodst + 4) = l1;
}

// -------- tiny pos-MLP device body: 2 branches x 43 rows x 6 heads --------
__device__ void ln_relu_lin(const float* x, const float* g, const float* b,
                            const float* W, const float* bb, float* y) {
    float mu = 0.f;
#pragma unroll
    for (int k = 0; k < PD; ++k) mu += x[k];
    mu *= (1.f / PD);
    float var = 0.f;
#pragma unroll
    for (int k = 0; k < PD; ++k) { float d = x[k] - mu; var += d * d; }
    var *= (1.f / PD);
    float r = rsqrtf(var + 1e-5f);
    float t[PD];
#pragma unroll
    for (int k = 0; k < PD; ++k) {
        float v = (x[k] - mu) * r * g[k] + b[k];
        t[k] = fmaxf(v, 0.f);
    }
#pragma unroll
    for (int p = 0; p < PD; ++p) {
        float s = bb[p];
#pragma unroll
        for (int k = 0; k < PD; ++k) s = fmaf(t[k], W[p * PD + k], s);
        y[p] = s;
    }
}

__device__ void pos_mlp_body(
    int t,
    const float* w0, const float* b0, const float* g1, const float* be1,
    const float* w1, const float* bb1, const float* g2, const float* be2,
    const float* w2, const float* bb2, const float* g3, const float* be3,
    const float* w3, const float* bb3, float* tab)
{
    if (t >= 2 * 43) return;
    int br = t / 43;
    int j = t - br * 43;
    float bx = -7.f, by = -7.f + (float)(j / 15), bz = -7.f + (float)(j % 15);
    float x[PD], y[PD];
    const float* W = w0 + br * (PD * 3);
#pragma unroll
    for (int p = 0; p < PD; ++p)
        x[p] = bx * W[p * 3 + 0] + by * W[p * 3 + 1] +
               bz * W[p * 3 + 2] + b0[br * PD + p];
    ln_relu_lin(x, g1 + br * PD, be1 + br * PD, w1 + br * PD * PD, bb1 + br * PD, y);
    ln_relu_lin(y, g2 + br * PD, be2 + br * PD, w2 + br * PD * PD, bb2 + br * PD, x);
    ln_relu_lin(x, g3 + br * PD, be3 + br * PD, w3 + br * HEADS * PD, bb3 + br * HEADS, y);
#pragma unroll
    for (int hh = 0; hh < HEADS; ++hh)
        tab[(br * HEADS + hh) * 64 + j] = y[hh];
}

// -------- prekernel: split grid/qkv into bf16 hi|lo rows + packed V + pos-MLP --------
__global__ __launch_bounds__(256) void pre_kernel(
    const float* __restrict__ qkv, const float* __restrict__ grd,
    u16* __restrict__ Gs, u16* __restrict__ K0s, u16* __restrict__ Q1s,
    u32* __restrict__ V0p,
    const float* w0, const float* b0, const float* g1, const float* be1,
    const float* w1, const float* bb1, const float* g2, const float* be2,
    const float* w2, const float* bb2, const float* g3, const float* be3,
    const float* w3, const float* bb3, float* __restrict__ tab)
{
    __shared__ u32 vt[16 * 128];
    const int bid = blockIdx.x;
    const int tid = threadIdx.x;
    if (bid >= 2304) {
        pos_mlp_body(tid, w0, b0, g1, be1, w1, bb1, g2, be2, w2, bb2,
                     g3, be3, w3, bb3, tab);
        return;
    }
    const int is_qkv = (bid >= 1152);
    const int lb = is_qkv ? bid - 1152 : bid;
    const int pair = lb >> 2, jb = lb & 3;
    const int b = pair / HEADS, h = pair - (pair / HEADS) * HEADS;
    const int row = tid >> 1, half = tid & 1;
    const int j = jb * 128 + row;

    if (!is_qkv) {
        const float* src = grd + ((size_t)b * NTOK + j) * 96 + h * HD + half * 8;
        u16* dst = Gs + ((size_t)pair * NTOK + j) * 40 + half * 8;
        split8_store(*(const float4*)src, *(const float4*)(src + 4), 1.f,
                     dst, dst + 16);
        return;
    }
    const float* base = qkv + ((size_t)b * NTOK + j) * 288 + h * HD + half * 8;
    {   // K slice (scaled)
        u16* dst = K0s + ((size_t)pair * NTOK + j) * 40 + half * 8;
        split8_store(*(const float4*)(base + 96), *(const float4*)(base + 100),
                     QSCALE, dst, dst + 16);
    }
    {   // Q slice (scaled)
        u16* dst = Q1s + ((size_t)pair * NTOK + j) * 40 + half * 8;
        split8_store(*(const float4*)base, *(const float4*)(base + 4),
                     QSCALE, dst, dst + 16);
    }
    {   // V slice -> packed transpose via LDS
        float4 a = *(const float4*)(base + 192);
        float4 c = *(const float4*)(base + 196);
        float vv[8] = {a.x, a.y, a.z, a.w, c.x, c.y, c.z, c.w};
#pragma unroll
        for (int s = 0; s < 8; ++s) {
            u16 hh, ll; split2(vv[s], hh, ll);
            vt[(half * 8 + s) * 128 + row] = (u32)hh | ((u32)ll << 16);
        }
    }
    __syncthreads();
    const int c = tid >> 4, jc = (tid & 15) * 8;
    u32* vdst = V0p + (size_t)pair * 8192 + c * NTOK + jb * 128 + jc;
    *(u32x4*)vdst = *(const u32x4*)&vt[c * 128 + jc];
    *(u32x4*)(vdst + 4) = *(const u32x4*)&vt[c * 128 + jc + 4];
}

// -------- MFMA attention pass (r8 attn3 + g-unroll + XCD swizzle) --------
// 2D grid (288 pairs, 4 row-blocks of 128 q-rows); linear wg id =
// pair + 288*rb, 288%8==0 -> all 4 row-blocks of a pair land on ONE XCD
// (K/V L2 locality). 256 thr = 4 waves; wave owns rows [Iblk+32w,+32) as
// two 16-row tiles. K rows staged PERMUTED so S^T's C-layout IS the PV
// B-operand layout (P register->register); V as A operand from packed
// [c][j]; l0 via ones-as-A MFMA (in-lane). The 4-trip g-loop is FULLY
// UNROLLED: r9 showed residency caps at ~10 waves/CU regardless of static
// occupancy, so cross-iteration ILP (exp(g) under S-mfma(g+1)) is the
// only way to hide the S->exp->pack->PV latency chain.
__global__ __launch_bounds__(256) void attn5_kernel(
    int pass, const u16* __restrict__ Qrows, const u16* __restrict__ Krows,
    const u32* __restrict__ Vpack, const float* __restrict__ tab,
    u32* __restrict__ xout, float* __restrict__ outp)
{
    __shared__ __align__(16) u16 sQ[128 * 48];   // [Qhi16|Qlo16|zeros16]
    __shared__ __align__(16) u16 sK[128 * 40];   // [Khi16|Klo16|pad8], permuted
    __shared__ __align__(16) f32x4 rt2[46];      // rpb*log2e, descending 4-tuple

    const int pair = blockIdx.x;
    const int rb = blockIdx.y;
    const int Iblk = rb * 128;
    const int b = pair / HEADS, h = pair - (pair / HEADS) * HEADS;
    const int tid = threadIdx.x, lane = tid & 63, w = tid >> 6;
    const int l15 = lane & 15, q = lane >> 4, q8 = q * 8;

    if (tid < 46) {
        const float* tb = tab + (pass * HEADS + h) * 64;
        f32x4 v;
#pragma unroll
        for (int c = 0; c < 4; ++c) {
            int ix = tid - c; ix = ix < 0 ? 0 : (ix > 42 ? 42 : ix);
            v[c] = tb[ix] * LOG2E;
        }
        rt2[tid] = v;
    }
    {   // stage Q rows (32 u16 payload each) into 48-stride rows + zero pad
        const u32* qsrc = (const u32*)(Qrows + ((size_t)pair * NTOK + Iblk) * 40);
#pragma unroll
        for (int k = 0; k < 2; ++k) {
            int item = tid + k * 256;
            int row = item >> 2, ch = item & 3;
            *(u32x4*)&((u32*)sQ)[row * 24 + ch * 4] =
                *(const u32x4*)&qsrc[row * 20 + ch * 4];
        }
#pragma unroll
        for (int k = 0; k < 4; ++k) {
            int item = tid + k * 256;
            ((u32*)sQ)[(item >> 3) * 24 + 16 + (item & 7)] = 0;
        }
    }
    __syncthreads();

    int sA[2];
    sA[0] = sigma(Iblk + w * 32 + l15) + 21;
    sA[1] = sigma(Iblk + w * 32 + 16 + l15) + 21;
    bf16x8 B1[2], B2[2];
#pragma unroll
    for (int qi = 0; qi < 2; ++qi) {
        int row = w * 32 + qi * 16 + l15;
        B1[qi] = *(const bf16x8*)&sQ[row * 48 + (q & 1) * 8];
        B2[qi] = *(const bf16x8*)&sQ[row * 48 + 16 + q8];
    }
    f32x4 accO[2] = {{0.f,0.f,0.f,0.f},{0.f,0.f,0.f,0.f}};
    f32x4 accL[2] = {{0.f,0.f,0.f,0.f},{0.f,0.f,0.f,0.f}};
    bf16x8 vones = {(short)0x3F80,(short)0x3F80,(short)0x3F80,(short)0x3F80,
                    (short)0x3F80,(short)0x3F80,(short)0x3F80,(short)0x3F80};
    const u32* vbase = Vpack + (size_t)pair * 8192 + l15 * NTOK;

    // K staging: thread copies half a row; target slot permuted so that
    // within each 32-token group, tile0 slot m holds token 8*(m>>2)+(m&3),
    // tile1 slot m holds that +4 (validated r8, absmax 9.8e-4).
    const int srow = tid >> 1, shalf = tid & 1;
    const int t5 = srow & 31;
    const int sslot = (srow & 96) +
                      (((t5 & 4) << 2) | ((t5 >> 3) << 2) | (t5 & 3));
    const u32* ksbase = (const u32*)(Krows + (size_t)pair * NTOK * 40);
    u32* kdst = (u32*)sK + sslot * 20 + shalf * 8;

    for (int step = 0; step < 4; ++step) {
        const int Jblk = step * 128;
        // prefetch this step's first V group BEFORE the barriers (no LDS dep)
        u32x4 va = *(const u32x4*)(vbase + Jblk + q8);
        u32x4 vb = *(const u32x4*)(vbase + Jblk + q8 + 4);
        __syncthreads();   // previous step's sK fully consumed
        {
            const u32* ks = ksbase + (size_t)(Jblk + srow) * 20 + shalf * 8;
            *(u32x4*)kdst = *(const u32x4*)ks;
            *(u32x4*)(kdst + 4) = *(const u32x4*)(ks + 4);
        }
        __syncthreads();

#pragma unroll
        for (int g = 0; g < 4; ++g) {
            u32x4 nva, nvb;
            if (g < 3) {
                nva = *(const u32x4*)(vbase + Jblk + (g + 1) * 32 + q8);
                nvb = *(const u32x4*)(vbase + Jblk + (g + 1) * 32 + q8 + 4);
            }
            const int sJg = sigma(Jblk + g * 32);   // wave-uniform
            bf16x8 A0 = *(const bf16x8*)&sK[(g * 32 + l15) * 40 + q8];
            bf16x8 A1 = *(const bf16x8*)&sK[(g * 32 + 16 + l15) * 40 + q8];
            union { u32 u[4]; bf16x8 v; } VH, VL;
            VH.u[0] = __builtin_amdgcn_perm(va.y, va.x, 0x05040100u);
            VH.u[1] = __builtin_amdgcn_perm(va.w, va.z, 0x05040100u);
            VH.u[2] = __builtin_amdgcn_perm(vb.y, vb.x, 0x05040100u);
            VH.u[3] = __builtin_amdgcn_perm(vb.w, vb.z, 0x05040100u);
            VL.u[0] = __builtin_amdgcn_perm(va.y, va.x, 0x07060302u);
            VL.u[1] = __builtin_amdgcn_perm(va.w, va.z, 0x07060302u);
            VL.u[2] = __builtin_amdgcn_perm(vb.y, vb.x, 0x07060302u);
            VL.u[3] = __builtin_amdgcn_perm(vb.w, vb.z, 0x07060302u);

#pragma unroll
            for (int qi = 0; qi < 2; ++qi) {
                f32x4 S0 = {0.f,0.f,0.f,0.f}, S1 = {0.f,0.f,0.f,0.f};
                S0 = __builtin_amdgcn_mfma_f32_16x16x32_bf16(A0, B1[qi], S0, 0, 0, 0);
                S0 = __builtin_amdgcn_mfma_f32_16x16x32_bf16(A0, B2[qi], S0, 0, 0, 0);
                S1 = __builtin_amdgcn_mfma_f32_16x16x32_bf16(A1, B1[qi], S1, 0, 0, 0);
                S1 = __builtin_amdgcn_mfma_f32_16x16x32_bf16(A1, B2[qi], S1, 0, 0, 0);
                // permuted rows: token(S0 reg r) = Jg + 8q + r -> rpb idx descends
                f32x4 rv0 = rt2[sA[qi] - sJg - q];
                f32x4 rv1 = rt2[sA[qi] - sJg - q - 4];
                u32 e0 = __float_as_uint(exp2f(S0.x + rv0.x));
                u32 e1 = __float_as_uint(exp2f(S0.y + rv0.y));
                u32 e2 = __float_as_uint(exp2f(S0.z + rv0.z));
                u32 e3 = __float_as_uint(exp2f(S0.w + rv0.w));
                u32 e4 = __float_as_uint(exp2f(S1.x + rv1.x));
                u32 e5 = __float_as_uint(exp2f(S1.y + rv1.y));
                u32 e6 = __float_as_uint(exp2f(S1.z + rv1.z));
                u32 e7 = __float_as_uint(exp2f(S1.w + rv1.w));
                union { u32 u[4]; bf16x8 v; } Pb;   // bf16-trunc pack, k-order
                Pb.u[0] = __builtin_amdgcn_perm(e1, e0, 0x07060302u);
                Pb.u[1] = __builtin_amdgcn_perm(e3, e2, 0x07060302u);
                Pb.u[2] = __builtin_amdgcn_perm(e5, e4, 0x07060302u);
                Pb.u[3] = __builtin_amdgcn_perm(e7, e6, 0x07060302u);
                accO[qi] = __builtin_amdgcn_mfma_f32_16x16x32_bf16(VH.v, Pb.v, accO[qi], 0, 0, 0);
                accO[qi] = __builtin_amdgcn_mfma_f32_16x16x32_bf16(VL.v, Pb.v, accO[qi], 0, 0, 0);
                accL[qi] = __builtin_amdgcn_mfma_f32_16x16x32_bf16(vones, Pb.v, accL[qi], 0, 0, 0);
            }
            if (g < 3) { va = nva; vb = nvb; }
        }
    }

    // ---- epilogue: accO = O^T[c=4q+reg][i=l15]; accL[*] = l0[i] in-lane ----
#pragma unroll
    for (int qi = 0; qi < 2; ++qi) {
        const float inv = 1.0f / accL[qi][0];
        const int i = Iblk + w * 32 + qi * 16 + l15;
        if (pass == 0) {
#pragma unroll
            for (int rg = 0; rg < 4; ++rg) {
                u16 hh, ll; split2(accO[qi][rg] * inv, hh, ll);
                xout[(size_t)pair * 8192 + (size_t)(4 * q + rg) * NTOK + i] =
                    (u32)hh | ((u32)ll << 16);
            }
        } else {
            float4 v = make_float4(accO[qi][0] * inv, accO[qi][1] * inv,
                                   accO[qi][2] * inv, accO[qi][3] * inv);
            *(float4*)&outp[((size_t)b * NTOK + i) * 96 + h * HD + 4 * q] = v;
        }
    }
}

// ================= fallback path (small ws): round-6 kernels =================
__global__ void pos_mlp_kernel(
    const float* w0, const float* b0, const float* g1, const float* be1,
    const float* w1, const float* bb1, const float* g2, const float* be2,
    const float* w2, const float* bb2, const float* g3, const float* be3,
    const float* w3, const float* bb3, float* tab)
{
    pos_mlp_body(threadIdx.x, w0, b0, g1, be1, w1, bb1, g2, be2, w2, bb2,
                 g3, be3, w3, bb3, tab);
}

__device__ __forceinline__ u32 rnd16(float p, float& l0acc) {
    u32 u = __float_as_uint(p);
    u32 r = u + 0x7fffu + ((u >> 16) & 1u);
    l0acc += __uint_as_float(r & 0xffff0000u);
    return r;
}

__global__ __launch_bounds__(256) void attn_v6_kernel(
    int pass,
    const float* __restrict__ qkv, const float* __restrict__ grd,
    const float* __restrict__ tab, float* __restrict__ xbuf,
    float* __restrict__ outp)
{
    __shared__ __align__(16) u16 sQ[128 * 48];
    __shared__ __align__(16) u16 sK[128 * 32];
    __shared__ __align__(16) u32 sV[16 * 132];
    __shared__ __align__(16) u16 sP[4 * 2 * 16 * 32];
    __shared__ __align__(16) f32x4 rt2[46];

    const int pair = blockIdx.x >> 2;
    const int rb   = blockIdx.x & 3;
    const int Iblk = rb * 128;
    const int b = pair / HEADS, h = pair - (pair / HEADS) * HEADS;
    const int tid = threadIdx.x;
    const int lane = tid & 63;
    const int w = tid >> 6;
    const int l15 = lane & 15;
    const int q = lane >> 4;
    const int q8 = q * 8;

    const float *qp, *kp, *vp, *tb;
    float* op;
    int qs, ks, vs, os;
    if (pass == 0) {
        qp = grd + (size_t)b * NTOK * 96 + h * HD;        qs = 96;
        kp = qkv + (size_t)b * NTOK * 288 + 96 + h * HD;  ks = 288;
        vp = kp + 96;                                     vs = 288;
        op = xbuf + (size_t)pair * NTOK * HD;             os = HD;
        tb = tab + h * 64;
    } else {
        qp = qkv + (size_t)b * NTOK * 288 + h * HD;       qs = 288;
        kp = grd + (size_t)b * NTOK * 96 + h * HD;        ks = 96;
        vp = xbuf + (size_t)pair * NTOK * HD;             vs = HD;
        op = outp + (size_t)b * NTOK * 96 + h * HD;       os = 96;
        tb = tab + (HEADS + h) * 64;
    }

#pragma unroll
    for (int k = 0; k < 2; ++k) {
        int item = tid + k * 256;
        int row = item >> 2, ch = item & 3;
        float4 u = *(const float4*)(qp + (size_t)(Iblk + row) * qs + ch * 4);
        ushort4 hi4, lo4;
        split2(u.x * QSCALE, hi4.x, lo4.x);
        split2(u.y * QSCALE, hi4.y, lo4.y);
        split2(u.z * QSCALE, hi4.z, lo4.z);
        split2(u.w * QSCALE, hi4.w, lo4.w);
        *(ushort4*)&sQ[row * 48 + ch * 4] = hi4;
        *(ushort4*)&sQ[row * 48 + 16 + ch * 4] = lo4;
    }
#pragma unroll
    for (int k = 0; k < 4; ++k) {
        int item = tid + k * 256;
        ((u32*)sQ)[(item >> 3) * 24 + 16 + (item & 7)] = 0;
    }
    if (tid < 46) {
        f32x4 v;
#pragma unroll
        for (int c = 0; c < 4; ++c) {
            int ix = tid - c; ix = ix < 0 ? 0 : (ix > 42 ? 42 : ix);
            v[c] = tb[ix] * LOG2E;
        }
        rt2[tid] = v;
    }
    __syncthreads();

    const int qoff = ((q & 1) << 2) | (q >> 1);
    int sA[2];
    sA[0] = sigma(Iblk + w * 32 + l15) + 21;
    sA[1] = sigma(Iblk + w * 32 + 16 + l15) + 21;
    bf16x8 B1[2], B2[2];
#pragma unroll
    for (int qi = 0; qi < 2; ++qi) {
        int row = w * 32 + qi * 16 + l15;
        B1[qi] = *(const bf16x8*)&sQ[row * 48 + (q & 1) * 8];
        B2[qi] = *(const bf16x8*)&sQ[row * 48 + 16 + q8];
    }
    f32x4 accO[2] = {{0.f,0.f,0.f,0.f},{0.f,0.f,0.f,0.f}};
    float l0a[2] = {0.f, 0.f};
    u32* sPu32 = (u32*)sP;

    for (int step = 0; step < 4; ++step) {
        const int Jblk = step * 128;
        if (step) __syncthreads();
#pragma unroll
        for (int k = 0; k < 2; ++k) {
            int item = tid + k * 256;
            int j = item >> 2, ch = item & 3;
            float4 u = *(const float4*)(kp + (size_t)(Jblk + j) * ks + ch * 4);
            ushort4 hi4, lo4;
            split2(u.x, hi4.x, lo4.x);
            split2(u.y, hi4.y, lo4.y);
            split2(u.z, hi4.z, lo4.z);
            split2(u.w, hi4.w, lo4.w);
            *(ushort4*)&sK[j * 32 + ch * 4] = hi4;
            *(ushort4*)&sK[j * 32 + 16 + ch * 4] = lo4;
            float4 vv = *(const float4*)(vp + (size_t)(Jblk + j) * vs + ch * 4);
            u16 vh, vl;
            split2(vv.x, vh, vl); sV[(ch * 4 + 0) * 132 + j] = (u32)vh | ((u32)vl << 16);
            split2(vv.y, vh, vl); sV[(ch * 4 + 1) * 132 + j] = (u32)vh | ((u32)vl << 16);
            split2(vv.z, vh, vl); sV[(ch * 4 + 2) * 132 + j] = (u32)vh | ((u32)vl << 16);
            split2(vv.w, vh, vl); sV[(ch * 4 + 3) * 132 + j] = (u32)vh | ((u32)vl << 16);
        }
        __syncthreads();

        for (int g = 0; g < 4; ++g) {
            const int sJ0 = sigma(Jblk + g * 32), sJ1 = sigma(Jblk + g * 32 + 16);
            bf16x8 A0 = *(const bf16x8*)&sK[(g * 32 + l15) * 32 + q8];
            bf16x8 A1 = *(const bf16x8*)&sK[(g * 32 + 16 + l15) * 32 + q8];
            const u32* vr = &sV[l15 * 132 + g * 32 + q8];
            u32x4 va = *(const u32x4*)vr;
            u32x4 vb = *(const u32x4*)(vr + 4);
            union { u32x4 u; bf16x8 hv; } BH, BL;
            BH.u[0] = __builtin_amdgcn_perm(va.y, va.x, 0x05040100u);
            BH.u[1] = __builtin_amdgcn_perm(va.w, va.z, 0x05040100u);
            BH.u[2] = __builtin_amdgcn_perm(vb.y, vb.x, 0x05040100u);
            BH.u[3] = __builtin_amdgcn_perm(vb.w, vb.z, 0x05040100u);
            BL.u[0] = __builtin_amdgcn_perm(va.y, va.x, 0x07060302u);
            BL.u[1] = __builtin_amdgcn_perm(va.w, va.z, 0x07060302u);
            BL.u[2] = __builtin_amdgcn_perm(vb.y, vb.x, 0x07060302u);
            BL.u[3] = __builtin_amdgcn_perm(vb.w, vb.z, 0x07060302u);

#pragma unroll
            for (int qi = 0; qi < 2; ++qi) {
                f32x4 S0 = {0.f,0.f,0.f,0.f}, S1 = {0.f,0.f,0.f,0.f};
                S0 = __builtin_amdgcn_mfma_f32_16x16x32_bf16(A0, B1[qi], S0, 0, 0, 0);
                S0 = __builtin_amdgcn_mfma_f32_16x16x32_bf16(A0, B2[qi], S0, 0, 0, 0);
                S1 = __builtin_amdgcn_mfma_f32_16x16x32_bf16(A1, B1[qi], S1, 0, 0, 0);
                S1 = __builtin_amdgcn_mfma_f32_16x16x32_bf16(A1, B2[qi], S1, 0, 0, 0);
                f32x4 rv0 = rt2[sA[qi] - sJ0 - qoff];
                f32x4 rv1 = rt2[sA[qi] - sJ1 - qoff];
                u32 r0 = rnd16(exp2f(S0.x + rv0.x), l0a[qi]);
                u32 r1 = rnd16(exp2f(S0.y + rv0.y), l0a[qi]);
                u32 r2 = rnd16(exp2f(S0.z + rv0.z), l0a[qi]);
                u32 r3 = rnd16(exp2f(S0.w + rv0.w), l0a[qi]);
                u32 pk01 = __builtin_amdgcn_perm(r1, r0, 0x07060302u);
                u32 pk23 = __builtin_amdgcn_perm(r3, r2, 0x07060302u);
                const int pbase = ((w * 2 + qi) * 16 + l15) * 16;
                *(uint2*)&sPu32[pbase + 2 * q] = make_uint2(pk01, pk23);
                r0 = rnd16(exp2f(S1.x + rv1.x), l0a[qi]);
                r1 = rnd16(exp2f(S1.y + rv1.y), l0a[qi]);
                r2 = rnd16(exp2f(S1.z + rv1.z), l0a[qi]);
                r3 = rnd16(exp2f(S1.w + rv1.w), l0a[qi]);
                pk01 = __builtin_amdgcn_perm(r1, r0, 0x07060302u);
                pk23 = __builtin_amdgcn_perm(r3, r2, 0x07060302u);
                *(uint2*)&sPu32[pbase + 8 + 2 * q] = make_uint2(pk01, pk23);
                bf16x8 Apv = *(const bf16x8*)&sP[((w * 2 + qi) * 16 + l15) * 32 + q8];
                accO[qi] = __builtin_amdgcn_mfma_f32_16x16x32_bf16(Apv, BH.hv, accO[qi], 0, 0, 0);
                accO[qi] = __builtin_amdgcn_mfma_f32_16x16x32_bf16(Apv, BL.hv, accO[qi], 0, 0, 0);
            }
        }
    }

#pragma unroll
    for (int qi = 0; qi < 2; ++qi) {
        float lt = l0a[qi];
        lt += __shfl_xor(lt, 16);
        lt += __shfl_xor(lt, 32);
#pragma unroll
        for (int rg = 0; rg < 4; ++rg) {
            float lr = __shfl(lt, q * 4 + rg);
            int ig = Iblk + w * 32 + qi * 16 + q * 4 + rg;
            op[(size_t)ig * os + l15] = accO[qi][rg] / lr;
        }
    }
}

extern "C" void kernel_launch(void* const* d_in, const int* in_sizes, int n_in,
                              void* d_out, int out_size, void* d_ws, size_t ws_size,
                              hipStream_t stream)
{
    const float* qkv = (const float*)d_in[0];
    const float* grd = (const float*)d_in[1];
    float* tab = (float*)d_ws;                          // 1024 f
    const size_t ROWS = (size_t)288 * NTOK;             // 147456 rows per tensor

    u32* xbuf = (u32*)(tab + 1024);                     // 288*8192 u32 = 9.44 MB
    u16* Gs   = (u16*)(xbuf + (size_t)288 * 8192);      // ROWS*40 u16 = 11.8 MB
    u16* K0s  = Gs + ROWS * 40;
    u16* Q1s  = K0s + ROWS * 40;
    u32* V0p  = (u32*)(Q1s + ROWS * 40);                // 9.44 MB
    const size_t NEEDED = 4096 + 9437184ull + 3ull * 11796480 + 9437184ull;

    if (ws_size >= NEEDED) {
        pre_kernel<<<2305, 256, 0, stream>>>(
            qkv, grd, Gs, K0s, Q1s, V0p,
            (const float*)d_in[2], (const float*)d_in[3],
            (const float*)d_in[4], (const float*)d_in[5],
            (const float*)d_in[6], (const float*)d_in[7],
            (const float*)d_in[8], (const float*)d_in[9],
            (const float*)d_in[10], (const float*)d_in[11],
            (const float*)d_in[12], (const float*)d_in[13],
            (const float*)d_in[14], (const float*)d_in[15],
            tab);
        dim3 agrid(288, 4);
        attn5_kernel<<<agrid, 256, 0, stream>>>(0, Gs, K0s, V0p, tab, xbuf, nullptr);
        attn5_kernel<<<agrid, 256, 0, stream>>>(1, Q1s, Gs, xbuf, tab, nullptr, (float*)d_out);
    } else {
        float* xf = (float*)d_ws + 1024;
        pos_mlp_kernel<<<1, 128, 0, stream>>>(
            (const float*)d_in[2], (const float*)d_in[3],
            (const float*)d_in[4], (const float*)d_in[5],
            (const float*)d_in[6], (const float*)d_in[7],
            (const float*)d_in[8], (const float*)d_in[9],
            (const float*)d_in[10], (const float*)d_in[11],
            (const float*)d_in[12], (const float*)d_in[13],
            (const float*)d_in[14], (const float*)d_in[15],
            tab);
        attn_v6_kernel<<<1152, 256, 0, stream>>>(0, qkv, grd, tab, xf, nullptr);
        attn_v6_kernel<<<1152, 256, 0, stream>>>(1, qkv, grd, tab, xf, (float*)d_out);
    }
}